// Round 9
// baseline (1113.458 us; speedup 1.0000x reference)
//
#include <hip/hip_runtime.h>
#include <hip/hip_cooperative_groups.h>
#include <stdint.h>

namespace cg = cooperative_groups;

#define NF 512
#define OUT_F 16
#define PAD_DEG 128
#define GBM 64
#define GBN 128
#define NBLK 768   // cooperative grid: 3 blocks/CU x 256 CUs (guaranteed by launch_bounds(256,3))

typedef __attribute__((ext_vector_type(8))) _Float16 half8;
typedef __attribute__((ext_vector_type(4))) _Float16 half4v;
typedef __attribute__((ext_vector_type(4))) float f32x4;

// async 16B/lane global->LDS: lds dst is wave-uniform base + lane*16
#define GLOAD_LDS16(g, l) \
  __builtin_amdgcn_global_load_lds((const __attribute__((address_space(1))) unsigned int*)(g), \
                                   (__attribute__((address_space(3))) unsigned int*)(l), 16, 0, 0)

// ---------------- device phase functions ----------------

// fp16 MFMA GEMM tile: Ch[m,:] = fp16(rsqrt(deg[m]+1) * (A[m,:] @ B)), 64x128 tile,
// 4 waves (2x2, wave tile 32x64), BK=64, global-side XOR chunk swizzle (conflict-free LDS).
__device__ __forceinline__ void gemm_tile(
    int job, const _Float16* __restrict__ A, const _Float16* __restrict__ BT,
    const int* __restrict__ counts, _Float16* __restrict__ Ch,
    _Float16* As, _Float16* Bs, int t) {
    int w = t >> 6, lane = t & 63, l15 = lane & 15, q = lane >> 4;
    int m0 = (job >> 2) * GBM;   // adjacent jobs share the A stripe
    int n0 = (job & 3) * GBN;
    int wr = w >> 1, wc = w & 1;

    int gr = lane >> 3;
    int gc = ((lane & 7) ^ (gr & 7)) * 8;
    const _Float16* Ag0 = A + (size_t)(m0 + w * 8 + gr) * NF + gc;
    const _Float16* Ag1 = A + (size_t)(m0 + 32 + w * 8 + gr) * NF + gc;
    const _Float16* Bg0 = BT + (size_t)(n0 + w * 8 + gr) * NF + gc;
    const _Float16* Bg1 = BT + (size_t)(n0 + 32 + w * 8 + gr) * NF + gc;
    const _Float16* Bg2 = BT + (size_t)(n0 + 64 + w * 8 + gr) * NF + gc;
    const _Float16* Bg3 = BT + (size_t)(n0 + 96 + w * 8 + gr) * NF + gc;
    _Float16* As_d0 = As + (w * 8) * 64;
    _Float16* As_d1 = As + (32 + w * 8) * 64;
    _Float16* Bs_d0 = Bs + (w * 8) * 64;
    _Float16* Bs_d1 = Bs + (32 + w * 8) * 64;
    _Float16* Bs_d2 = Bs + (64 + w * 8) * 64;
    _Float16* Bs_d3 = Bs + (96 + w * 8) * 64;

    f32x4 acc[2][4] = {};

    for (int k0 = 0; k0 < NF; k0 += 64) {
        GLOAD_LDS16(Ag0 + k0, As_d0);
        GLOAD_LDS16(Ag1 + k0, As_d1);
        GLOAD_LDS16(Bg0 + k0, Bs_d0);
        GLOAD_LDS16(Bg1 + k0, Bs_d1);
        GLOAD_LDS16(Bg2 + k0, Bs_d2);
        GLOAD_LDS16(Bg3 + k0, Bs_d3);
        __syncthreads();

        int key = l15 & 7;
#pragma unroll
        for (int kk = 0; kk < 2; ++kk) {
            int ch = ((kk * 4 + q) ^ key) * 8;
            half8 a[2], b[4];
#pragma unroll
            for (int r = 0; r < 2; ++r)
                a[r] = *(const half8*)(As + (wr * 32 + r * 16 + l15) * 64 + ch);
#pragma unroll
            for (int c = 0; c < 4; ++c)
                b[c] = *(const half8*)(Bs + (wc * 64 + c * 16 + l15) * 64 + ch);
#pragma unroll
            for (int r = 0; r < 2; ++r)
#pragma unroll
                for (int c = 0; c < 4; ++c)
                    acc[r][c] = __builtin_amdgcn_mfma_f32_16x16x32_f16(a[r], b[c], acc[r][c], 0, 0, 0);
        }
        __syncthreads();
    }

    // C/D layout: col = l15, row = q*4 + reg
#pragma unroll
    for (int r = 0; r < 2; ++r)
#pragma unroll
        for (int i = 0; i < 4; ++i) {
            int row = m0 + wr * 32 + r * 16 + q * 4 + i;
            float dv = rsqrtf((float)counts[row] + 1.0f);
#pragma unroll
            for (int c = 0; c < 4; ++c) {
                int col = n0 + wc * 64 + c * 16 + l15;
                Ch[(size_t)row * NF + col] = (_Float16)(acc[r][c][i] * dv);
            }
        }
}

// quarter-wave chunked CSR aggregation job (XCD-L2-resident 128-feature chunks):
// job jb -> chunk jb&3, nodes (jb>>2)*4 + wave. lane = 16g+j; quarter g takes 4 edges;
// lane loads half8 (16 B); butterfly-reduce across quarters; emit fp16.
__device__ __forceinline__ void agg_job(
    int jb, const _Float16* __restrict__ hb, const int* __restrict__ counts,
    const int* __restrict__ src_pad, const float* __restrict__ bias,
    _Float16* __restrict__ out_h, int Mreal, int t) {
    int chunk = jb & 3;
    int node = (jb >> 2) * 4 + (t >> 6);
    int lane = t & 63;
    int g = lane >> 4;
    int j = lane & 15;
    int f8 = chunk * 128 + j * 8;
    size_t obase = (size_t)node * NF + f8;

    if (node >= Mreal) {  // pad rows must be zero when consumed as GEMM-A
        if (g == 0) {
            half8 z = {0, 0, 0, 0, 0, 0, 0, 0};
            *(half8*)(out_h + obase) = z;
        }
        return;
    }

    int cntr = counts[node];
    int cnt = cntr < PAD_DEG ? cntr : PAD_DEG;
    const int* sp = src_pad + (size_t)node * PAD_DEG;

    float acc[8] = {};
    for (int e = 0; e < cnt; e += 16) {
        int4 s4 = *(const int4*)(sp + e + g * 4);
        int base = e + g * 4;
        int sidx[4] = {s4.x, s4.y, s4.z, s4.w};
#pragma unroll
        for (int tq = 0; tq < 4; ++tq) {
            bool ok = (base + tq) < cnt;
            int srow = ok ? sidx[tq] : node;
            float m = ok ? 1.f : 0.f;
            half8 hv = *(const half8*)(hb + (size_t)srow * NF + f8);
#pragma unroll
            for (int k = 0; k < 8; ++k) acc[k] = fmaf(m, (float)hv[k], acc[k]);
        }
    }

#pragma unroll
    for (int k = 0; k < 8; ++k) {
        acc[k] += __shfl_xor(acc[k], 16);
        acc[k] += __shfl_xor(acc[k], 32);
    }

    if (g != 0) return;

    half8 sv = *(const half8*)(hb + obase);
    float dv = rsqrtf((float)cntr + 1.0f);
    half8 o8;
#pragma unroll
    for (int k = 0; k < 8; ++k) {
        float o = fmaxf(fmaf(dv, acc[k] + (float)sv[k], bias[f8 + k]), 0.f);
        o8[k] = (_Float16)o;
    }
    *(half8*)(out_h + obase) = o8;
}

union SmemU {
    _Float16 g[GBM * 64 + GBN * 64];  // 24 KB gemm staging
    float wtile[64][65];              // 16.6 KB W transpose
    float ws[NF * OUT_F];             // 32 KB head weights
};

// ---------------- cooperative fused kernel ----------------

__global__ __launch_bounds__(256, 3) void fused_kernel(
    const float* __restrict__ x, const int* __restrict__ src, const int* __restrict__ dst,
    const float* __restrict__ W1, const float* __restrict__ b1,
    const float* __restrict__ W2, const float* __restrict__ b2,
    const float* __restrict__ Wl, const float* __restrict__ bl,
    _Float16* __restrict__ hbuf, _Float16* __restrict__ abuf,
    _Float16* __restrict__ W1T, _Float16* __restrict__ W2T,
    int* __restrict__ counts, int* __restrict__ src_pad, float* __restrict__ out,
    int E, int Nreal, int Mp) {
    cg::grid_group grid = cg::this_grid();
    __shared__ SmemU smem;
    const int b = blockIdx.x;
    const int t = threadIdx.x;

    // ---- phase 0a: zero counts ----
    for (int i = b * 256 + t; i < Mp; i += NBLK * 256) counts[i] = 0;
    __threadfence();
    grid.sync();

    // ---- phase 0b: W transpose->fp16 | x->fp16 | edge prep ----
    if (b < 128) {
        int id = b;
        const float* W; _Float16* WT;
        if (id < 64) { W = W1; WT = W1T; }
        else         { W = W2; WT = W2T; id -= 64; }
        int k0 = (id & 7) * 64, n0 = (id >> 3) * 64;
        int tr = t >> 4, tc4 = (t & 15) * 4;
#pragma unroll
        for (int i = 0; i < 4; ++i) {
            int r = tr + i * 16;
            float4 v = *(const float4*)(W + (size_t)(k0 + r) * NF + n0 + tc4);
            smem.wtile[r][tc4 + 0] = v.x; smem.wtile[r][tc4 + 1] = v.y;
            smem.wtile[r][tc4 + 2] = v.z; smem.wtile[r][tc4 + 3] = v.w;
        }
        __syncthreads();
#pragma unroll
        for (int i = 0; i < 4; ++i) {
            int n = tr + i * 16;
            half4v hv;
#pragma unroll
            for (int jj = 0; jj < 4; ++jj) hv[jj] = (_Float16)smem.wtile[tc4 + jj][n];
            *(half4v*)(WT + (size_t)(n0 + n) * NF + k0 + tc4) = hv;
        }
    }
    for (int jx = b; jx < Mp / 4; jx += NBLK) {
        int idx = jx * 256 + t;
        int row = idx >> 6;
        int c8 = (idx & 63) * 8;
        half8 hv = {0, 0, 0, 0, 0, 0, 0, 0};
        if (row < Nreal) {
            float4 v0 = *(const float4*)(x + (size_t)row * NF + c8);
            float4 v1 = *(const float4*)(x + (size_t)row * NF + c8 + 4);
            hv[0] = (_Float16)v0.x; hv[1] = (_Float16)v0.y;
            hv[2] = (_Float16)v0.z; hv[3] = (_Float16)v0.w;
            hv[4] = (_Float16)v1.x; hv[5] = (_Float16)v1.y;
            hv[6] = (_Float16)v1.z; hv[7] = (_Float16)v1.w;
        }
        *(half8*)(abuf + (size_t)row * NF + c8) = hv;
    }
    int ejobs = (E + 255) / 256;
    for (int je = b; je < ejobs; je += NBLK) {
        int e = je * 256 + t;
        if (e < E) {
            int d = dst[e];
            int slot = atomicAdd(&counts[d], 1);
            if (slot < PAD_DEG) src_pad[(size_t)d * PAD_DEG + slot] = src[e];
        }
    }
    __threadfence();
    grid.sync();

    int gjobs = (Mp / GBM) * (NF / GBN);  // 632

    // ---- phase 1: gemm1 ----
    if (b < gjobs) gemm_tile(b, abuf, W1T, counts, hbuf, smem.g, smem.g + GBM * 64, t);
    __threadfence();
    grid.sync();

    // ---- phase 2: agg1 -> abuf ----
    for (int jb = b; jb < Mp; jb += NBLK) agg_job(jb, hbuf, counts, src_pad, b1, abuf, Nreal, t);
    __threadfence();
    grid.sync();

    // ---- phase 3: gemm2 ----
    if (b < gjobs) gemm_tile(b, abuf, W2T, counts, hbuf, smem.g, smem.g + GBM * 64, t);
    __threadfence();
    grid.sync();

    // ---- phase 4: agg2 -> abuf ----
    for (int jb = b; jb < Mp; jb += NBLK) agg_job(jb, hbuf, counts, src_pad, b2, abuf, Nreal, t);
    __threadfence();
    grid.sync();

    // ---- phase 5: head ----
    if (b < (Nreal + 15) / 16) {
        for (int i = t; i < NF * OUT_F; i += 256) smem.ws[i] = Wl[i];
        __syncthreads();
        int node = b * 16 + (t >> 4);
        int o = t & 15;
        if (node < Nreal) {
            const half8* row8 = (const half8*)(abuf + (size_t)node * NF);
            float acc = 0.f;
#pragma unroll 2
            for (int k8 = 0; k8 < NF / 8; ++k8) {
                half8 hv = row8[k8];
                int kb = k8 * 8;
#pragma unroll
                for (int u = 0; u < 8; ++u)
                    acc = fmaf((float)hv[u], smem.ws[(kb + u) * OUT_F + o], acc);
            }
            out[(size_t)node * OUT_F + o] = acc + bl[o];
        }
    }
}

// ---------------- fallback multi-dispatch kernels (used only if coop launch fails) ----------------

__global__ __launch_bounds__(256) void fb_prep_kernel(
    const float* __restrict__ W1, const float* __restrict__ W2,
    _Float16* __restrict__ T1, _Float16* __restrict__ T2,
    const float* __restrict__ x, _Float16* __restrict__ x16,
    const int* __restrict__ src, const int* __restrict__ dst,
    int* __restrict__ counts, int* __restrict__ src_pad,
    int E, int Nreal, int Mp) {
    __shared__ float tile[64][65];
    int b = blockIdx.x;
    int xblocks = Mp / 4;
    if (b < 128) {
        int id = b;
        const float* W; _Float16* WT;
        if (id < 64) { W = W1; WT = T1; }
        else         { W = W2; WT = T2; id -= 64; }
        int k0 = (id & 7) * 64, n0 = (id >> 3) * 64;
        int tr = threadIdx.x >> 4, tc4 = (threadIdx.x & 15) * 4;
#pragma unroll
        for (int i = 0; i < 4; ++i) {
            int r = tr + i * 16;
            float4 v = *(const float4*)(W + (size_t)(k0 + r) * NF + n0 + tc4);
            tile[r][tc4 + 0] = v.x; tile[r][tc4 + 1] = v.y;
            tile[r][tc4 + 2] = v.z; tile[r][tc4 + 3] = v.w;
        }
        __syncthreads();
#pragma unroll
        for (int i = 0; i < 4; ++i) {
            int n = tr + i * 16;
            half4v hv;
#pragma unroll
            for (int jj = 0; jj < 4; ++jj) hv[jj] = (_Float16)tile[tc4 + jj][n];
            *(half4v*)(WT + (size_t)(n0 + n) * NF + k0 + tc4) = hv;
        }
    } else if (b < 128 + xblocks) {
        int idx = (b - 128) * 256 + threadIdx.x;
        int row = idx >> 6;
        int c8 = (idx & 63) * 8;
        if (row >= Mp) return;
        half8 hv = {0, 0, 0, 0, 0, 0, 0, 0};
        if (row < Nreal) {
            float4 v0 = *(const float4*)(x + (size_t)row * NF + c8);
            float4 v1 = *(const float4*)(x + (size_t)row * NF + c8 + 4);
            hv[0] = (_Float16)v0.x; hv[1] = (_Float16)v0.y;
            hv[2] = (_Float16)v0.z; hv[3] = (_Float16)v0.w;
            hv[4] = (_Float16)v1.x; hv[5] = (_Float16)v1.y;
            hv[6] = (_Float16)v1.z; hv[7] = (_Float16)v1.w;
        }
        *(half8*)(x16 + (size_t)row * NF + c8) = hv;
    } else {
        int e = (b - 128 - xblocks) * 256 + threadIdx.x;
        if (e < E) {
            int d = dst[e];
            int slot = atomicAdd(&counts[d], 1);
            if (slot < PAD_DEG) src_pad[(size_t)d * PAD_DEG + slot] = src[e];
        }
    }
}

__global__ __launch_bounds__(256) void fb_gemm_kernel(
    const _Float16* __restrict__ A, const _Float16* __restrict__ BT,
    const int* __restrict__ counts, _Float16* __restrict__ Ch) {
    __shared__ _Float16 lds[GBM * 64 + GBN * 64];
    gemm_tile(blockIdx.x, A, BT, counts, Ch, lds, lds + GBM * 64, threadIdx.x);
}

__global__ __launch_bounds__(256) void fb_agg_kernel(
    const _Float16* __restrict__ hb, const int* __restrict__ counts,
    const int* __restrict__ src_pad, const float* __restrict__ bias,
    _Float16* __restrict__ out_h, int Mreal) {
    agg_job(blockIdx.x, hb, counts, src_pad, bias, out_h, Mreal, threadIdx.x);
}

__global__ __launch_bounds__(256) void fb_head_kernel(
    const _Float16* __restrict__ in, const float* __restrict__ Wl,
    const float* __restrict__ bl, float* __restrict__ out, int M) {
    __shared__ float Ws[NF * OUT_F];
    int tid = threadIdx.x;
    for (int i = tid; i < NF * OUT_F; i += 256) Ws[i] = Wl[i];
    __syncthreads();
    int node = blockIdx.x * 16 + (tid >> 4);
    int o = tid & 15;
    if (node >= M) return;
    const half8* row8 = (const half8*)(in + (size_t)node * NF);
    float acc = 0.f;
#pragma unroll 2
    for (int k8 = 0; k8 < NF / 8; ++k8) {
        half8 hv = row8[k8];
        int kb = k8 * 8;
#pragma unroll
        for (int u = 0; u < 8; ++u)
            acc = fmaf((float)hv[u], Ws[(kb + u) * OUT_F + o], acc);
    }
    out[(size_t)node * OUT_F + o] = acc + bl[o];
}

// ---------------- launch ----------------

extern "C" void kernel_launch(void* const* d_in, const int* in_sizes, int n_in,
                              void* d_out, int out_size, void* d_ws, size_t ws_size,
                              hipStream_t stream) {
    const float* x  = (const float*)d_in[0];
    const int* eidx = (const int*)d_in[1];
    const float* W1 = (const float*)d_in[2];
    const float* b1 = (const float*)d_in[3];
    const float* W2 = (const float*)d_in[4];
    const float* b2 = (const float*)d_in[5];
    const float* Wl = (const float*)d_in[6];
    const float* bl = (const float*)d_in[7];

    int N = in_sizes[0] / NF;
    int E = in_sizes[1] / 2;
    int Mp = (N + GBM - 1) & ~(GBM - 1);
    const int* src = eidx;
    const int* dst = eidx + E;

    char* p = (char*)d_ws;
    auto carve = [&](size_t bytes) -> void* {
        void* r = (void*)p;
        p += (bytes + 255) & ~(size_t)255;
        return r;
    };
    _Float16* hbuf = (_Float16*)carve((size_t)Mp * NF * sizeof(_Float16));
    _Float16* abuf = (_Float16*)carve((size_t)Mp * NF * sizeof(_Float16));
    _Float16* W1T  = (_Float16*)carve((size_t)NF * NF * sizeof(_Float16));
    _Float16* W2T  = (_Float16*)carve((size_t)NF * NF * sizeof(_Float16));
    int* counts    = (int*)carve((size_t)Mp * sizeof(int));
    int* src_pad   = (int*)carve((size_t)N * PAD_DEG * sizeof(int));
    float* outp    = (float*)d_out;

    void* args[] = {
        (void*)&x, (void*)&src, (void*)&dst, (void*)&W1, (void*)&b1,
        (void*)&W2, (void*)&b2, (void*)&Wl, (void*)&bl,
        (void*)&hbuf, (void*)&abuf, (void*)&W1T, (void*)&W2T,
        (void*)&counts, (void*)&src_pad, (void*)&outp,
        (void*)&E, (void*)&N, (void*)&Mp
    };
    hipError_t err = hipLaunchCooperativeKernel((void*)fused_kernel, dim3(NBLK), dim3(256),
                                                args, 0, stream);
    if (err != hipSuccess) {
        // deterministic fallback: multi-dispatch path (same device code)
        hipMemsetAsync(counts, 0, (size_t)Mp * sizeof(int), stream);
        int xblocks = Mp / 4;
        int eblocks = (E + 255) / 256;
        fb_prep_kernel<<<dim3(128 + xblocks + eblocks), dim3(256), 0, stream>>>(
            W1, W2, W1T, W2T, x, abuf, src, dst, counts, src_pad, E, N, Mp);
        dim3 gg((Mp / GBM) * (NF / GBN));
        dim3 ga(Mp);
        fb_gemm_kernel<<<gg, dim3(256), 0, stream>>>(abuf, W1T, counts, hbuf);
        fb_agg_kernel<<<ga, dim3(256), 0, stream>>>(hbuf, counts, src_pad, b1, abuf, N);
        fb_gemm_kernel<<<gg, dim3(256), 0, stream>>>(abuf, W2T, counts, hbuf);
        fb_agg_kernel<<<ga, dim3(256), 0, stream>>>(hbuf, counts, src_pad, b2, abuf, N);
        fb_head_kernel<<<dim3((N + 15) / 16), dim3(256), 0, stream>>>(abuf, Wl, bl, outp, N);
    }
}

// Round 10
// 187.682 us; speedup vs baseline: 5.9327x; 5.9327x over previous
//
#include <hip/hip_runtime.h>
#include <stdint.h>

#define NF 512
#define OUT_F 16
#define PAD_DEG 64
#define GBM 64
#define GBN 128

typedef __attribute__((ext_vector_type(8))) _Float16 half8;
typedef __attribute__((ext_vector_type(4))) _Float16 half4v;
typedef __attribute__((ext_vector_type(4))) float f32x4;

// async 16B/lane global->LDS: lds dst is wave-uniform base + lane*16
#define GLOAD_LDS16(g, l) \
  __builtin_amdgcn_global_load_lds((const __attribute__((address_space(1))) unsigned int*)(g), \
                                   (__attribute__((address_space(3))) unsigned int*)(l), 16, 0, 0)

// ---------- fused prep: [0,128) convert W1/W2 | [128,128+Mp/4) convert x | rest edge prep ----------

__global__ __launch_bounds__(256) void prep_kernel(
    const float* __restrict__ W1, const float* __restrict__ W2,
    _Float16* __restrict__ T1, _Float16* __restrict__ T2,
    const float* __restrict__ x, _Float16* __restrict__ x16,
    const int* __restrict__ src, const int* __restrict__ dst,
    int* __restrict__ counts, int* __restrict__ src_pad,
    int E, int Nreal, int Mp) {
    __shared__ float tile[64][65];
    int b = blockIdx.x;
    int xblocks = Mp / 4;

    if (b < 128) {
        // ---- weight transpose + fp16: W[k][n] -> WT[n][k] ----
        int id = b;
        const float* W;  _Float16* WT;
        if (id < 64) { W = W1; WT = T1; }
        else         { W = W2; WT = T2; id -= 64; }
        int k0 = (id & 7) * 64, n0 = (id >> 3) * 64;
        int tr = threadIdx.x >> 4;
        int tc4 = (threadIdx.x & 15) * 4;
#pragma unroll
        for (int i = 0; i < 4; ++i) {
            int r = tr + i * 16;
            float4 v = *(const float4*)(W + (size_t)(k0 + r) * NF + n0 + tc4);
            tile[r][tc4 + 0] = v.x; tile[r][tc4 + 1] = v.y;
            tile[r][tc4 + 2] = v.z; tile[r][tc4 + 3] = v.w;
        }
        __syncthreads();
#pragma unroll
        for (int i = 0; i < 4; ++i) {
            int n = tr + i * 16;
            half4v hv;
#pragma unroll
            for (int j = 0; j < 4; ++j) hv[j] = (_Float16)tile[tc4 + j][n];
            *(half4v*)(WT + (size_t)(n0 + n) * NF + k0 + tc4) = hv;
        }
    } else if (b < 128 + xblocks) {
        // ---- x fp32 -> fp16, zero pad rows ----
        int idx = (b - 128) * 256 + threadIdx.x;  // one half8 per thread
        int row = idx >> 6;
        int c8 = (idx & 63) * 8;
        if (row >= Mp) return;
        half8 hv = {0, 0, 0, 0, 0, 0, 0, 0};
        if (row < Nreal) {
            float4 v0 = *(const float4*)(x + (size_t)row * NF + c8);
            float4 v1 = *(const float4*)(x + (size_t)row * NF + c8 + 4);
            hv[0] = (_Float16)v0.x; hv[1] = (_Float16)v0.y;
            hv[2] = (_Float16)v0.z; hv[3] = (_Float16)v0.w;
            hv[4] = (_Float16)v1.x; hv[5] = (_Float16)v1.y;
            hv[6] = (_Float16)v1.z; hv[7] = (_Float16)v1.w;
        }
        *(half8*)(x16 + (size_t)row * NF + c8) = hv;
    } else {
        // ---- edge prep: in-degree count + padded adjacency ----
        int e = (b - 128 - xblocks) * 256 + threadIdx.x;
        if (e < E) {
            int d = dst[e];
            int slot = atomicAdd(&counts[d], 1);
            if (slot < PAD_DEG) src_pad[(size_t)d * PAD_DEG + slot] = src[e];
        }
    }
}

// ---------- fp16 MFMA GEMM: Ch[m,:] = fp16(rsqrt(deg[m]+1) * (A[m,:] @ B)) ----------
// 64x128 tile, 4 waves (2x2, wave tile 32x64), BK=64.
// LDS chunk-XOR swizzle applied on the GLOBAL side (global_load_lds forces lane->LDS contiguity).

__global__ __launch_bounds__(256) void gemm_mfma_kernel(
    const _Float16* __restrict__ A, const _Float16* __restrict__ BT,
    const int* __restrict__ counts, _Float16* __restrict__ Ch) {
    __shared__ _Float16 lds[GBM * 64 + GBN * 64];  // 24 KB: As[64][64] | Bs[128][64]
    _Float16* As = lds;
    _Float16* Bs = lds + GBM * 64;

    int t = threadIdx.x;
    int w = t >> 6, lane = t & 63, l15 = lane & 15, q = lane >> 4;
    int m0 = (blockIdx.x >> 2) * GBM;   // adjacent blocks share the A stripe
    int n0 = (blockIdx.x & 3) * GBN;
    int wr = w >> 1, wc = w & 1;        // 2x2 wave grid; wave tile 32x64

    int gr = lane >> 3;
    int gc = ((lane & 7) ^ (gr & 7)) * 8;
    const _Float16* Ag0 = A + (size_t)(m0 + w * 8 + gr) * NF + gc;
    const _Float16* Ag1 = A + (size_t)(m0 + 32 + w * 8 + gr) * NF + gc;
    const _Float16* Bg0 = BT + (size_t)(n0 + w * 8 + gr) * NF + gc;
    const _Float16* Bg1 = BT + (size_t)(n0 + 32 + w * 8 + gr) * NF + gc;
    const _Float16* Bg2 = BT + (size_t)(n0 + 64 + w * 8 + gr) * NF + gc;
    const _Float16* Bg3 = BT + (size_t)(n0 + 96 + w * 8 + gr) * NF + gc;
    _Float16* As_d0 = As + (w * 8) * 64;
    _Float16* As_d1 = As + (32 + w * 8) * 64;
    _Float16* Bs_d0 = Bs + (w * 8) * 64;
    _Float16* Bs_d1 = Bs + (32 + w * 8) * 64;
    _Float16* Bs_d2 = Bs + (64 + w * 8) * 64;
    _Float16* Bs_d3 = Bs + (96 + w * 8) * 64;

    f32x4 acc[2][4] = {};

    for (int k0 = 0; k0 < NF; k0 += 64) {
        GLOAD_LDS16(Ag0 + k0, As_d0);
        GLOAD_LDS16(Ag1 + k0, As_d1);
        GLOAD_LDS16(Bg0 + k0, Bs_d0);
        GLOAD_LDS16(Bg1 + k0, Bs_d1);
        GLOAD_LDS16(Bg2 + k0, Bs_d2);
        GLOAD_LDS16(Bg3 + k0, Bs_d3);
        __syncthreads();

        int key = l15 & 7;
#pragma unroll
        for (int kk = 0; kk < 2; ++kk) {
            int ch = ((kk * 4 + q) ^ key) * 8;  // swizzled k-chunk for this lane
            half8 a[2], b[4];
#pragma unroll
            for (int r = 0; r < 2; ++r)
                a[r] = *(const half8*)(As + (wr * 32 + r * 16 + l15) * 64 + ch);
#pragma unroll
            for (int c = 0; c < 4; ++c)
                b[c] = *(const half8*)(Bs + (wc * 64 + c * 16 + l15) * 64 + ch);
#pragma unroll
            for (int r = 0; r < 2; ++r)
#pragma unroll
                for (int c = 0; c < 4; ++c)
                    acc[r][c] = __builtin_amdgcn_mfma_f32_16x16x32_f16(a[r], b[c], acc[r][c], 0, 0, 0);
        }
        __syncthreads();
    }

    // C/D layout: col = l15, row = q*4 + reg
#pragma unroll
    for (int r = 0; r < 2; ++r)
#pragma unroll
        for (int i = 0; i < 4; ++i) {
            int row = m0 + wr * 32 + r * 16 + q * 4 + i;
            float dv = rsqrtf((float)counts[row] + 1.0f);
#pragma unroll
            for (int c = 0; c < 4; ++c) {
                int col = n0 + wc * 64 + c * 16 + l15;
                Ch[(size_t)row * NF + col] = (_Float16)(acc[r][c][i] * dv);
            }
        }
}

// ---------- shared gather: one wave per node, full 512-feature row, fp32 accumulate ----------
// returns o[8] = relu(dinv*(sum + self) + bias) for this lane's 8 features; false if pad node.

__device__ __forceinline__ void gather_row(
    int node, int lane, const _Float16* __restrict__ hb, const int* __restrict__ counts,
    const int* __restrict__ src_pad, const float* __restrict__ bias, float o[8]) {
    int f8 = lane * 8;
    size_t obase = (size_t)node * NF + f8;
    int cntr = counts[node];
    int cnt = cntr < PAD_DEG ? cntr : PAD_DEG;
    const int* sp = src_pad + (size_t)node * PAD_DEG;

    half8 sv = *(const half8*)(hb + obase);  // self row (overlaps with gather)
    float4 b0 = *(const float4*)(bias + f8);
    float4 b1 = *(const float4*)(bias + f8 + 4);

    float acc[8] = {};
    int e = 0;
    for (; e + 7 < cnt; e += 8) {  // 8 gathers in flight (latency hiding)
        half8 v[8];
#pragma unroll
        for (int u = 0; u < 8; ++u) {
            int s = sp[e + u];
            v[u] = *(const half8*)(hb + (size_t)s * NF + f8);
        }
#pragma unroll
        for (int k = 0; k < 8; ++k)
            acc[k] += (((float)v[0][k] + (float)v[1][k]) + ((float)v[2][k] + (float)v[3][k]))
                    + (((float)v[4][k] + (float)v[5][k]) + ((float)v[6][k] + (float)v[7][k]));
    }
    for (; e + 3 < cnt; e += 4) {
        int s0 = sp[e], s1 = sp[e + 1], s2 = sp[e + 2], s3 = sp[e + 3];
        half8 v0 = *(const half8*)(hb + (size_t)s0 * NF + f8);
        half8 v1 = *(const half8*)(hb + (size_t)s1 * NF + f8);
        half8 v2 = *(const half8*)(hb + (size_t)s2 * NF + f8);
        half8 v3 = *(const half8*)(hb + (size_t)s3 * NF + f8);
#pragma unroll
        for (int k = 0; k < 8; ++k)
            acc[k] += ((float)v0[k] + (float)v1[k]) + ((float)v2[k] + (float)v3[k]);
    }
    for (; e < cnt; ++e) {
        int s = sp[e];
        half8 v = *(const half8*)(hb + (size_t)s * NF + f8);
#pragma unroll
        for (int k = 0; k < 8; ++k) acc[k] += (float)v[k];
    }

    float dv = rsqrtf((float)cntr + 1.0f);
    float bb[8] = {b0.x, b0.y, b0.z, b0.w, b1.x, b1.y, b1.z, b1.w};
#pragma unroll
    for (int k = 0; k < 8; ++k)
        o[k] = fmaxf(fmaf(dv, acc[k] + (float)sv[k], bb[k]), 0.f);
}

// ---------- agg1: gather + emit fp16 row (gemm2's A; pad rows zeroed) ----------

__global__ __launch_bounds__(256) void agg_kernel(
    const _Float16* __restrict__ hb, const int* __restrict__ counts,
    const int* __restrict__ src_pad, const float* __restrict__ bias,
    _Float16* __restrict__ out_h, int Mreal) {
    int node = __builtin_amdgcn_readfirstlane(blockIdx.x * 4 + (threadIdx.x >> 6));
    int lane = threadIdx.x & 63;
    size_t obase = (size_t)node * NF + lane * 8;

    if (node >= Mreal) {  // pad rows must be zero when consumed as GEMM-A
        half8 z = {0, 0, 0, 0, 0, 0, 0, 0};
        *(half8*)(out_h + obase) = z;
        return;
    }
    float o[8];
    gather_row(node, lane, hb, counts, src_pad, bias, o);
    half8 o8;
#pragma unroll
    for (int k = 0; k < 8; ++k) o8[k] = (_Float16)o[k];
    *(half8*)(out_h + obase) = o8;
}

// ---------- agg2 + fused head: gather h2 row in-wave, then logits = h2 @ Wl + bl ----------
// Wave holds the full 512-feat row (8/lane). Lane computes 16 partial dots against its
// 8 Wl rows (global reads; 32 KB Wl is L1-resident per CU); 6-step butterfly sums across
// lanes; lane 0 stores the 16 logits. No h2 write to memory at all.

__global__ __launch_bounds__(256) void agg_head_kernel(
    const _Float16* __restrict__ hb, const int* __restrict__ counts,
    const int* __restrict__ src_pad, const float* __restrict__ bias,
    const float* __restrict__ Wl, const float* __restrict__ bl,
    float* __restrict__ out, int Mreal) {
    int node = __builtin_amdgcn_readfirstlane(blockIdx.x * 4 + (threadIdx.x >> 6));
    if (node >= Mreal) return;
    int lane = threadIdx.x & 63;
    int f8 = lane * 8;

    float o[8];
    gather_row(node, lane, hb, counts, src_pad, bias, o);

    float p[16] = {};
#pragma unroll
    for (int k = 0; k < 8; ++k) {
        const float4* wr = (const float4*)(Wl + (size_t)(f8 + k) * OUT_F);
        float4 w0 = wr[0], w1 = wr[1], w2 = wr[2], w3 = wr[3];
        p[0]  = fmaf(o[k], w0.x, p[0]);  p[1]  = fmaf(o[k], w0.y, p[1]);
        p[2]  = fmaf(o[k], w0.z, p[2]);  p[3]  = fmaf(o[k], w0.w, p[3]);
        p[4]  = fmaf(o[k], w1.x, p[4]);  p[5]  = fmaf(o[k], w1.y, p[5]);
        p[6]  = fmaf(o[k], w1.z, p[6]);  p[7]  = fmaf(o[k], w1.w, p[7]);
        p[8]  = fmaf(o[k], w2.x, p[8]);  p[9]  = fmaf(o[k], w2.y, p[9]);
        p[10] = fmaf(o[k], w2.z, p[10]); p[11] = fmaf(o[k], w2.w, p[11]);
        p[12] = fmaf(o[k], w3.x, p[12]); p[13] = fmaf(o[k], w3.y, p[13]);
        p[14] = fmaf(o[k], w3.z, p[14]); p[15] = fmaf(o[k], w3.w, p[15]);
    }
#pragma unroll
    for (int st = 1; st < 64; st <<= 1)
#pragma unroll
        for (int j = 0; j < 16; ++j) p[j] += __shfl_xor(p[j], st);

    if (lane == 0) {
#pragma unroll
        for (int j = 0; j < 16; ++j)
            out[(size_t)node * OUT_F + j] = p[j] + bl[j];
    }
}

// ---------- launch ----------

extern "C" void kernel_launch(void* const* d_in, const int* in_sizes, int n_in,
                              void* d_out, int out_size, void* d_ws, size_t ws_size,
                              hipStream_t stream) {
    const float* x  = (const float*)d_in[0];
    const int* eidx = (const int*)d_in[1];
    const float* W1 = (const float*)d_in[2];
    const float* b1 = (const float*)d_in[3];
    const float* W2 = (const float*)d_in[4];
    const float* b2 = (const float*)d_in[5];
    const float* Wl = (const float*)d_in[6];
    const float* bl = (const float*)d_in[7];

    int N = in_sizes[0] / NF;
    int E = in_sizes[1] / 2;
    int Mp = (N + GBM - 1) & ~(GBM - 1);
    const int* src = eidx;
    const int* dst = eidx + E;

    char* p = (char*)d_ws;
    auto carve = [&](size_t bytes) -> void* {
        void* r = (void*)p;
        p += (bytes + 255) & ~(size_t)255;
        return r;
    };
    _Float16* hbuf = (_Float16*)carve((size_t)Mp * NF * sizeof(_Float16));  // GEMM outputs
    _Float16* abuf = (_Float16*)carve((size_t)Mp * NF * sizeof(_Float16));  // x16 / agg1 out
    _Float16* W1T  = (_Float16*)carve((size_t)NF * NF * sizeof(_Float16));
    _Float16* W2T  = (_Float16*)carve((size_t)NF * NF * sizeof(_Float16));
    int* counts    = (int*)carve((size_t)Mp * sizeof(int));
    int* src_pad   = (int*)carve((size_t)N * PAD_DEG * sizeof(int));

    hipMemsetAsync(counts, 0, (size_t)Mp * sizeof(int), stream);

    int xblocks = Mp / 4;
    int eblocks = (E + 255) / 256;
    prep_kernel<<<dim3(128 + xblocks + eblocks), dim3(256), 0, stream>>>(
        W1, W2, W1T, W2T, x, abuf, src, dst, counts, src_pad, E, N, Mp);

    dim3 gg((Mp / GBM) * (NF / GBN));   // 632 blocks

    // layer 1
    gemm_mfma_kernel<<<gg, dim3(256), 0, stream>>>(abuf, W1T, counts, hbuf);
    agg_kernel<<<dim3(Mp / 4), dim3(256), 0, stream>>>(hbuf, counts, src_pad, b1, abuf, N);
    // layer 2 + fused head
    gemm_mfma_kernel<<<gg, dim3(256), 0, stream>>>(abuf, W2T, counts, hbuf);
    agg_head_kernel<<<dim3((N + 3) / 4), dim3(256), 0, stream>>>(
        hbuf, counts, src_pad, b2, Wl, bl, (float*)d_out, N);
}

// Round 11
// 170.667 us; speedup vs baseline: 6.5241x; 1.0997x over previous
//
#include <hip/hip_runtime.h>
#include <stdint.h>

#define NF 512
#define OUT_F 16
#define PAD_DEG 64
#define GBM 64
#define GBN 128

typedef __attribute__((ext_vector_type(8))) _Float16 half8;
typedef __attribute__((ext_vector_type(4))) _Float16 half4v;
typedef __attribute__((ext_vector_type(4))) float f32x4;

// async 16B/lane global->LDS: lds dst is wave-uniform base + lane*16
#define GLOAD_LDS16(g, l) \
  __builtin_amdgcn_global_load_lds((const __attribute__((address_space(1))) unsigned int*)(g), \
                                   (__attribute__((address_space(3))) unsigned int*)(l), 16, 0, 0)

// ---------- fused prep: [0,128) convert W1/W2 | [128,128+Mp/4) convert x | rest edge prep ----------

__global__ __launch_bounds__(256) void prep_kernel(
    const float* __restrict__ W1, const float* __restrict__ W2,
    _Float16* __restrict__ T1, _Float16* __restrict__ T2,
    const float* __restrict__ x, _Float16* __restrict__ x16,
    const int* __restrict__ src, const int* __restrict__ dst,
    int* __restrict__ counts, int* __restrict__ src_pad,
    int E, int Nreal, int Mp) {
    __shared__ float tile[64][65];
    int b = blockIdx.x;
    int xblocks = Mp / 4;

    if (b < 128) {
        // ---- weight transpose + fp16: W[k][n] -> WT[n][k] ----
        int id = b;
        const float* W;  _Float16* WT;
        if (id < 64) { W = W1; WT = T1; }
        else         { W = W2; WT = T2; id -= 64; }
        int k0 = (id & 7) * 64, n0 = (id >> 3) * 64;
        int tr = threadIdx.x >> 4;
        int tc4 = (threadIdx.x & 15) * 4;
#pragma unroll
        for (int i = 0; i < 4; ++i) {
            int r = tr + i * 16;
            float4 v = *(const float4*)(W + (size_t)(k0 + r) * NF + n0 + tc4);
            tile[r][tc4 + 0] = v.x; tile[r][tc4 + 1] = v.y;
            tile[r][tc4 + 2] = v.z; tile[r][tc4 + 3] = v.w;
        }
        __syncthreads();
#pragma unroll
        for (int i = 0; i < 4; ++i) {
            int n = tr + i * 16;
            half4v hv;
#pragma unroll
            for (int j = 0; j < 4; ++j) hv[j] = (_Float16)tile[tc4 + j][n];
            *(half4v*)(WT + (size_t)(n0 + n) * NF + k0 + tc4) = hv;
        }
    } else if (b < 128 + xblocks) {
        // ---- x fp32 -> fp16, zero pad rows ----
        int idx = (b - 128) * 256 + threadIdx.x;  // one half8 per thread
        int row = idx >> 6;
        int c8 = (idx & 63) * 8;
        if (row >= Mp) return;
        half8 hv = {0, 0, 0, 0, 0, 0, 0, 0};
        if (row < Nreal) {
            float4 v0 = *(const float4*)(x + (size_t)row * NF + c8);
            float4 v1 = *(const float4*)(x + (size_t)row * NF + c8 + 4);
            hv[0] = (_Float16)v0.x; hv[1] = (_Float16)v0.y;
            hv[2] = (_Float16)v0.z; hv[3] = (_Float16)v0.w;
            hv[4] = (_Float16)v1.x; hv[5] = (_Float16)v1.y;
            hv[6] = (_Float16)v1.z; hv[7] = (_Float16)v1.w;
        }
        *(half8*)(x16 + (size_t)row * NF + c8) = hv;
    } else {
        // ---- edge prep: in-degree count + padded adjacency ----
        int e = (b - 128 - xblocks) * 256 + threadIdx.x;
        if (e < E) {
            int d = dst[e];
            int slot = atomicAdd(&counts[d], 1);
            if (slot < PAD_DEG) src_pad[(size_t)d * PAD_DEG + slot] = src[e];
        }
    }
}

// ---------- fp16 MFMA GEMM: Ch[m,:] = fp16(rsqrt(deg[m]+1) * (A[m,:] @ B)) ----------
// 64x128 tile, 4 waves (2x2, wave tile 32x64), BK=64.
// LDS chunk-XOR swizzle applied on the GLOBAL side (global_load_lds forces lane->LDS contiguity).

__global__ __launch_bounds__(256) void gemm_mfma_kernel(
    const _Float16* __restrict__ A, const _Float16* __restrict__ BT,
    const int* __restrict__ counts, _Float16* __restrict__ Ch) {
    __shared__ _Float16 lds[GBM * 64 + GBN * 64];  // 24 KB: As[64][64] | Bs[128][64]
    _Float16* As = lds;
    _Float16* Bs = lds + GBM * 64;

    int t = threadIdx.x;
    int w = t >> 6, lane = t & 63, l15 = lane & 15, q = lane >> 4;
    int m0 = (blockIdx.x >> 2) * GBM;   // adjacent blocks share the A stripe
    int n0 = (blockIdx.x & 3) * GBN;
    int wr = w >> 1, wc = w & 1;        // 2x2 wave grid; wave tile 32x64

    int gr = lane >> 3;
    int gc = ((lane & 7) ^ (gr & 7)) * 8;
    const _Float16* Ag0 = A + (size_t)(m0 + w * 8 + gr) * NF + gc;
    const _Float16* Ag1 = A + (size_t)(m0 + 32 + w * 8 + gr) * NF + gc;
    const _Float16* Bg0 = BT + (size_t)(n0 + w * 8 + gr) * NF + gc;
    const _Float16* Bg1 = BT + (size_t)(n0 + 32 + w * 8 + gr) * NF + gc;
    const _Float16* Bg2 = BT + (size_t)(n0 + 64 + w * 8 + gr) * NF + gc;
    const _Float16* Bg3 = BT + (size_t)(n0 + 96 + w * 8 + gr) * NF + gc;
    _Float16* As_d0 = As + (w * 8) * 64;
    _Float16* As_d1 = As + (32 + w * 8) * 64;
    _Float16* Bs_d0 = Bs + (w * 8) * 64;
    _Float16* Bs_d1 = Bs + (32 + w * 8) * 64;
    _Float16* Bs_d2 = Bs + (64 + w * 8) * 64;
    _Float16* Bs_d3 = Bs + (96 + w * 8) * 64;

    f32x4 acc[2][4] = {};

    for (int k0 = 0; k0 < NF; k0 += 64) {
        GLOAD_LDS16(Ag0 + k0, As_d0);
        GLOAD_LDS16(Ag1 + k0, As_d1);
        GLOAD_LDS16(Bg0 + k0, Bs_d0);
        GLOAD_LDS16(Bg1 + k0, Bs_d1);
        GLOAD_LDS16(Bg2 + k0, Bs_d2);
        GLOAD_LDS16(Bg3 + k0, Bs_d3);
        __syncthreads();

        int key = l15 & 7;
#pragma unroll
        for (int kk = 0; kk < 2; ++kk) {
            int ch = ((kk * 4 + q) ^ key) * 8;  // swizzled k-chunk for this lane
            half8 a[2], b[4];
#pragma unroll
            for (int r = 0; r < 2; ++r)
                a[r] = *(const half8*)(As + (wr * 32 + r * 16 + l15) * 64 + ch);
#pragma unroll
            for (int c = 0; c < 4; ++c)
                b[c] = *(const half8*)(Bs + (wc * 64 + c * 16 + l15) * 64 + ch);
#pragma unroll
            for (int r = 0; r < 2; ++r)
#pragma unroll
                for (int c = 0; c < 4; ++c)
                    acc[r][c] = __builtin_amdgcn_mfma_f32_16x16x32_f16(a[r], b[c], acc[r][c], 0, 0, 0);
        }
        __syncthreads();
    }

    // C/D layout: col = l15, row = q*4 + reg
#pragma unroll
    for (int r = 0; r < 2; ++r)
#pragma unroll
        for (int i = 0; i < 4; ++i) {
            int row = m0 + wr * 32 + r * 16 + q * 4 + i;
            float dv = rsqrtf((float)counts[row] + 1.0f);
#pragma unroll
            for (int c = 0; c < 4; ++c) {
                int col = n0 + wc * 64 + c * 16 + l15;
                Ch[(size_t)row * NF + col] = (_Float16)(acc[r][c][i] * dv);
            }
        }
}

// ---------- one-wave-per-node CSR aggregation over fp16 h-buffer ----------
// Wave-uniform node -> counts/src_pad reads are SCALAR loads; each edge gather is ONE
// 1 KB vector load (64 lanes x half8); 8 gathers kept in flight. Emits fp16 row.

__global__ __launch_bounds__(256) void agg_kernel(
    const _Float16* __restrict__ hb, const int* __restrict__ counts,
    const int* __restrict__ src_pad, const float* __restrict__ bias,
    _Float16* __restrict__ out_h, int Mreal) {
    int node = __builtin_amdgcn_readfirstlane(blockIdx.x * 4 + (threadIdx.x >> 6));
    int lane = threadIdx.x & 63;
    int f8 = lane * 8;
    size_t obase = (size_t)node * NF + f8;

    if (node >= Mreal) {  // pad rows must be zero when consumed as GEMM-A
        half8 z = {0, 0, 0, 0, 0, 0, 0, 0};
        *(half8*)(out_h + obase) = z;
        return;
    }

    int cntr = counts[node];
    int cnt = cntr < PAD_DEG ? cntr : PAD_DEG;
    const int* sp = src_pad + (size_t)node * PAD_DEG;

    half8 sv = *(const half8*)(hb + obase);  // self row (overlaps with gather)
    float4 b0 = *(const float4*)(bias + f8);
    float4 b1 = *(const float4*)(bias + f8 + 4);

    float acc[8] = {};
    int e = 0;
    for (; e + 7 < cnt; e += 8) {  // 8 gathers in flight
        half8 v[8];
#pragma unroll
        for (int u = 0; u < 8; ++u) {
            int s = sp[e + u];
            v[u] = *(const half8*)(hb + (size_t)s * NF + f8);
        }
#pragma unroll
        for (int k = 0; k < 8; ++k)
            acc[k] += (((float)v[0][k] + (float)v[1][k]) + ((float)v[2][k] + (float)v[3][k]))
                    + (((float)v[4][k] + (float)v[5][k]) + ((float)v[6][k] + (float)v[7][k]));
    }
    for (; e + 3 < cnt; e += 4) {
        int s0 = sp[e], s1 = sp[e + 1], s2 = sp[e + 2], s3 = sp[e + 3];
        half8 v0 = *(const half8*)(hb + (size_t)s0 * NF + f8);
        half8 v1 = *(const half8*)(hb + (size_t)s1 * NF + f8);
        half8 v2 = *(const half8*)(hb + (size_t)s2 * NF + f8);
        half8 v3 = *(const half8*)(hb + (size_t)s3 * NF + f8);
#pragma unroll
        for (int k = 0; k < 8; ++k)
            acc[k] += ((float)v0[k] + (float)v1[k]) + ((float)v2[k] + (float)v3[k]);
    }
    for (; e < cnt; ++e) {
        int s = sp[e];
        half8 v = *(const half8*)(hb + (size_t)s * NF + f8);
#pragma unroll
        for (int k = 0; k < 8; ++k) acc[k] += (float)v[k];
    }

    float dv = rsqrtf((float)cntr + 1.0f);
    float bb[8] = {b0.x, b0.y, b0.z, b0.w, b1.x, b1.y, b1.z, b1.w};
    half8 o8;
#pragma unroll
    for (int k = 0; k < 8; ++k) {
        float o = fmaxf(fmaf(dv, acc[k] + (float)sv[k], bb[k]), 0.f);
        o8[k] = (_Float16)o;
    }
    *(half8*)(out_h + obase) = o8;
}

// ---------- head: out[n,o] = h2[n,:] @ Wl[:,o] + bl[o]  (fp16 in, fp32 out) ----------

__global__ __launch_bounds__(256) void head_kernel(
    const _Float16* __restrict__ in, const float* __restrict__ Wl,
    const float* __restrict__ bl, float* __restrict__ out, int M) {
    __shared__ float Ws[NF * OUT_F];  // 32 KB
    int tid = threadIdx.x;
    for (int i = tid; i < NF * OUT_F; i += 256) Ws[i] = Wl[i];
    __syncthreads();
    int node = blockIdx.x * 16 + (tid >> 4);
    int o = tid & 15;
    if (node >= M) return;
    const half8* row8 = (const half8*)(in + (size_t)node * NF);
    float acc = 0.f;
#pragma unroll 2
    for (int k8 = 0; k8 < NF / 8; ++k8) {
        half8 hv = row8[k8];
        int kb = k8 * 8;
#pragma unroll
        for (int u = 0; u < 8; ++u)
            acc = fmaf((float)hv[u], Ws[(kb + u) * OUT_F + o], acc);
    }
    out[(size_t)node * OUT_F + o] = acc + bl[o];
}

// ---------- launch ----------

extern "C" void kernel_launch(void* const* d_in, const int* in_sizes, int n_in,
                              void* d_out, int out_size, void* d_ws, size_t ws_size,
                              hipStream_t stream) {
    const float* x  = (const float*)d_in[0];
    const int* eidx = (const int*)d_in[1];
    const float* W1 = (const float*)d_in[2];
    const float* b1 = (const float*)d_in[3];
    const float* W2 = (const float*)d_in[4];
    const float* b2 = (const float*)d_in[5];
    const float* Wl = (const float*)d_in[6];
    const float* bl = (const float*)d_in[7];

    int N = in_sizes[0] / NF;
    int E = in_sizes[1] / 2;
    int Mp = (N + GBM - 1) & ~(GBM - 1);
    const int* src = eidx;
    const int* dst = eidx + E;

    char* p = (char*)d_ws;
    auto carve = [&](size_t bytes) -> void* {
        void* r = (void*)p;
        p += (bytes + 255) & ~(size_t)255;
        return r;
    };
    _Float16* hbuf = (_Float16*)carve((size_t)Mp * NF * sizeof(_Float16));  // GEMM outputs
    _Float16* abuf = (_Float16*)carve((size_t)Mp * NF * sizeof(_Float16));  // x16 / agg outs
    _Float16* W1T  = (_Float16*)carve((size_t)NF * NF * sizeof(_Float16));
    _Float16* W2T  = (_Float16*)carve((size_t)NF * NF * sizeof(_Float16));
    int* counts    = (int*)carve((size_t)Mp * sizeof(int));
    int* src_pad   = (int*)carve((size_t)N * PAD_DEG * sizeof(int));

    hipMemsetAsync(counts, 0, (size_t)Mp * sizeof(int), stream);

    int xblocks = Mp / 4;
    int eblocks = (E + 255) / 256;
    prep_kernel<<<dim3(128 + xblocks + eblocks), dim3(256), 0, stream>>>(
        W1, W2, W1T, W2T, x, abuf, src, dst, counts, src_pad, E, N, Mp);

    dim3 gg((Mp / GBM) * (NF / GBN));   // 628 blocks
    dim3 ga(Mp / 4);                    // one wave per node

    // layer 1
    gemm_mfma_kernel<<<gg, dim3(256), 0, stream>>>(abuf, W1T, counts, hbuf);
    agg_kernel<<<ga, dim3(256), 0, stream>>>(hbuf, counts, src_pad, b1, abuf, N);
    // layer 2
    gemm_mfma_kernel<<<gg, dim3(256), 0, stream>>>(abuf, W2T, counts, hbuf);
    agg_kernel<<<ga, dim3(256), 0, stream>>>(hbuf, counts, src_pad, b2, abuf, N);
    // head
    head_kernel<<<dim3((N + 15) / 16), dim3(256), 0, stream>>>(abuf, Wl, bl, (float*)d_out, N);
}

// Round 12
// 168.899 us; speedup vs baseline: 6.5925x; 1.0105x over previous
//
#include <hip/hip_runtime.h>
#include <stdint.h>

#define NF 512
#define OUT_F 16
#define PAD_DEG 64
#define GBM 64
#define GBN 128

typedef __attribute__((ext_vector_type(8))) _Float16 half8;
typedef __attribute__((ext_vector_type(4))) _Float16 half4v;
typedef __attribute__((ext_vector_type(4))) float f32x4;

// async 16B/lane global->LDS: lds dst is wave-uniform base + lane*16
#define GLOAD_LDS16(g, l) \
  __builtin_amdgcn_global_load_lds((const __attribute__((address_space(1))) unsigned int*)(g), \
                                   (__attribute__((address_space(3))) unsigned int*)(l), 16, 0, 0)

// ---------- fused prep: [0,128) convert W1/W2 | [128,128+Mp/4) convert x | rest edge prep ----------

__global__ __launch_bounds__(256) void prep_kernel(
    const float* __restrict__ W1, const float* __restrict__ W2,
    _Float16* __restrict__ T1, _Float16* __restrict__ T2,
    const float* __restrict__ x, _Float16* __restrict__ x16,
    const int* __restrict__ src, const int* __restrict__ dst,
    int* __restrict__ counts, int* __restrict__ src_pad,
    int E, int Nreal, int Mp) {
    __shared__ float tile[64][65];
    int b = blockIdx.x;
    int xblocks = Mp / 4;

    if (b < 128) {
        // ---- weight transpose + fp16: W[k][n] -> WT[n][k] ----
        int id = b;
        const float* W;  _Float16* WT;
        if (id < 64) { W = W1; WT = T1; }
        else         { W = W2; WT = T2; id -= 64; }
        int k0 = (id & 7) * 64, n0 = (id >> 3) * 64;
        int tr = threadIdx.x >> 4;
        int tc4 = (threadIdx.x & 15) * 4;
#pragma unroll
        for (int i = 0; i < 4; ++i) {
            int r = tr + i * 16;
            float4 v = *(const float4*)(W + (size_t)(k0 + r) * NF + n0 + tc4);
            tile[r][tc4 + 0] = v.x; tile[r][tc4 + 1] = v.y;
            tile[r][tc4 + 2] = v.z; tile[r][tc4 + 3] = v.w;
        }
        __syncthreads();
#pragma unroll
        for (int i = 0; i < 4; ++i) {
            int n = tr + i * 16;
            half4v hv;
#pragma unroll
            for (int j = 0; j < 4; ++j) hv[j] = (_Float16)tile[tc4 + j][n];
            *(half4v*)(WT + (size_t)(n0 + n) * NF + k0 + tc4) = hv;
        }
    } else if (b < 128 + xblocks) {
        // ---- x fp32 -> fp16, zero pad rows ----
        int idx = (b - 128) * 256 + threadIdx.x;  // one half8 per thread
        int row = idx >> 6;
        int c8 = (idx & 63) * 8;
        if (row >= Mp) return;
        half8 hv = {0, 0, 0, 0, 0, 0, 0, 0};
        if (row < Nreal) {
            float4 v0 = *(const float4*)(x + (size_t)row * NF + c8);
            float4 v1 = *(const float4*)(x + (size_t)row * NF + c8 + 4);
            hv[0] = (_Float16)v0.x; hv[1] = (_Float16)v0.y;
            hv[2] = (_Float16)v0.z; hv[3] = (_Float16)v0.w;
            hv[4] = (_Float16)v1.x; hv[5] = (_Float16)v1.y;
            hv[6] = (_Float16)v1.z; hv[7] = (_Float16)v1.w;
        }
        *(half8*)(x16 + (size_t)row * NF + c8) = hv;
    } else {
        // ---- edge prep: in-degree count + padded adjacency ----
        int e = (b - 128 - xblocks) * 256 + threadIdx.x;
        if (e < E) {
            int d = dst[e];
            int slot = atomicAdd(&counts[d], 1);
            if (slot < PAD_DEG) src_pad[(size_t)d * PAD_DEG + slot] = src[e];
        }
    }
}

// ---------- fp16 MFMA GEMM: Ch[m,:] = fp16(rsqrt(deg[m]+1) * (A[m,:] @ B)) ----------
// 64x128 tile, 4 waves (2x2, wave tile 32x64), BK=64.
// XCD-pinned job map: blockIdx%8 == stripe%8, so all 4 column-jobs of one A-stripe
// run on the SAME XCD (A fetched once into that XCD's L2, not 4x from LLC).
// LDS chunk-XOR swizzle applied on the GLOBAL side (global_load_lds forces lane->LDS contiguity).

__global__ __launch_bounds__(256) void gemm_mfma_kernel(
    const _Float16* __restrict__ A, const _Float16* __restrict__ BT,
    const int* __restrict__ counts, _Float16* __restrict__ Ch, int nstripes) {
    __shared__ _Float16 lds[GBM * 64 + GBN * 64];  // 24 KB: As[64][64] | Bs[128][64]
    _Float16* As = lds;
    _Float16* Bs = lds + GBM * 64;

    int b = blockIdx.x;
    int xcd = b & 7;               // hardware round-robin: XCD = blockIdx % 8
    int r = b >> 3;
    int s = xcd + 8 * (r >> 2);    // stripe with s % 8 == xcd
    if (s >= nstripes) return;
    int m0 = s * GBM;
    int n0 = (r & 3) * GBN;

    int t = threadIdx.x;
    int w = t >> 6, lane = t & 63, l15 = lane & 15, q = lane >> 4;
    int wr = w >> 1, wc = w & 1;        // 2x2 wave grid; wave tile 32x64

    int gr = lane >> 3;
    int gc = ((lane & 7) ^ (gr & 7)) * 8;
    const _Float16* Ag0 = A + (size_t)(m0 + w * 8 + gr) * NF + gc;
    const _Float16* Ag1 = A + (size_t)(m0 + 32 + w * 8 + gr) * NF + gc;
    const _Float16* Bg0 = BT + (size_t)(n0 + w * 8 + gr) * NF + gc;
    const _Float16* Bg1 = BT + (size_t)(n0 + 32 + w * 8 + gr) * NF + gc;
    const _Float16* Bg2 = BT + (size_t)(n0 + 64 + w * 8 + gr) * NF + gc;
    const _Float16* Bg3 = BT + (size_t)(n0 + 96 + w * 8 + gr) * NF + gc;
    _Float16* As_d0 = As + (w * 8) * 64;
    _Float16* As_d1 = As + (32 + w * 8) * 64;
    _Float16* Bs_d0 = Bs + (w * 8) * 64;
    _Float16* Bs_d1 = Bs + (32 + w * 8) * 64;
    _Float16* Bs_d2 = Bs + (64 + w * 8) * 64;
    _Float16* Bs_d3 = Bs + (96 + w * 8) * 64;

    f32x4 acc[2][4] = {};

    for (int k0 = 0; k0 < NF; k0 += 64) {
        GLOAD_LDS16(Ag0 + k0, As_d0);
        GLOAD_LDS16(Ag1 + k0, As_d1);
        GLOAD_LDS16(Bg0 + k0, Bs_d0);
        GLOAD_LDS16(Bg1 + k0, Bs_d1);
        GLOAD_LDS16(Bg2 + k0, Bs_d2);
        GLOAD_LDS16(Bg3 + k0, Bs_d3);
        __syncthreads();

        int key = l15 & 7;
#pragma unroll
        for (int kk = 0; kk < 2; ++kk) {
            int ch = ((kk * 4 + q) ^ key) * 8;  // swizzled k-chunk for this lane
            half8 a[2], b2[4];
#pragma unroll
            for (int rr = 0; rr < 2; ++rr)
                a[rr] = *(const half8*)(As + (wr * 32 + rr * 16 + l15) * 64 + ch);
#pragma unroll
            for (int c = 0; c < 4; ++c)
                b2[c] = *(const half8*)(Bs + (wc * 64 + c * 16 + l15) * 64 + ch);
#pragma unroll
            for (int rr = 0; rr < 2; ++rr)
#pragma unroll
                for (int c = 0; c < 4; ++c)
                    acc[rr][c] = __builtin_amdgcn_mfma_f32_16x16x32_f16(a[rr], b2[c], acc[rr][c], 0, 0, 0);
        }
        __syncthreads();
    }

    // C/D layout: col = l15, row = q*4 + reg
#pragma unroll
    for (int rr = 0; rr < 2; ++rr)
#pragma unroll
        for (int i = 0; i < 4; ++i) {
            int row = m0 + wr * 32 + rr * 16 + q * 4 + i;
            float dv = rsqrtf((float)counts[row] + 1.0f);
#pragma unroll
            for (int c = 0; c < 4; ++c) {
                int col = n0 + wc * 64 + c * 16 + l15;
                Ch[(size_t)row * NF + col] = (_Float16)(acc[rr][c][i] * dv);
            }
        }
}

// ---------- one-wave-per-node CSR aggregation over fp16 h-buffer ----------
// Wave-uniform node -> counts/src_pad reads are SCALAR loads; each edge gather is ONE
// 1 KB vector load (64 lanes x half8); 8 gathers kept in flight. Emits fp16 row.

__global__ __launch_bounds__(256) void agg_kernel(
    const _Float16* __restrict__ hb, const int* __restrict__ counts,
    const int* __restrict__ src_pad, const float* __restrict__ bias,
    _Float16* __restrict__ out_h, int Mreal) {
    int node = __builtin_amdgcn_readfirstlane(blockIdx.x * 4 + (threadIdx.x >> 6));
    int lane = threadIdx.x & 63;
    int f8 = lane * 8;
    size_t obase = (size_t)node * NF + f8;

    if (node >= Mreal) {  // pad rows must be zero when consumed as GEMM-A
        half8 z = {0, 0, 0, 0, 0, 0, 0, 0};
        *(half8*)(out_h + obase) = z;
        return;
    }

    int cntr = counts[node];
    int cnt = cntr < PAD_DEG ? cntr : PAD_DEG;
    const int* sp = src_pad + (size_t)node * PAD_DEG;

    half8 sv = *(const half8*)(hb + obase);  // self row (overlaps with gather)
    float4 b0 = *(const float4*)(bias + f8);
    float4 b1 = *(const float4*)(bias + f8 + 4);

    float acc[8] = {};
    int e = 0;
    for (; e + 7 < cnt; e += 8) {  // 8 gathers in flight
        half8 v[8];
#pragma unroll
        for (int u = 0; u < 8; ++u) {
            int s = sp[e + u];
            v[u] = *(const half8*)(hb + (size_t)s * NF + f8);
        }
#pragma unroll
        for (int k = 0; k < 8; ++k)
            acc[k] += (((float)v[0][k] + (float)v[1][k]) + ((float)v[2][k] + (float)v[3][k]))
                    + (((float)v[4][k] + (float)v[5][k]) + ((float)v[6][k] + (float)v[7][k]));
    }
    for (; e + 3 < cnt; e += 4) {
        int s0 = sp[e], s1 = sp[e + 1], s2 = sp[e + 2], s3 = sp[e + 3];
        half8 v0 = *(const half8*)(hb + (size_t)s0 * NF + f8);
        half8 v1 = *(const half8*)(hb + (size_t)s1 * NF + f8);
        half8 v2 = *(const half8*)(hb + (size_t)s2 * NF + f8);
        half8 v3 = *(const half8*)(hb + (size_t)s3 * NF + f8);
#pragma unroll
        for (int k = 0; k < 8; ++k)
            acc[k] += ((float)v0[k] + (float)v1[k]) + ((float)v2[k] + (float)v3[k]);
    }
    for (; e < cnt; ++e) {
        int s = sp[e];
        half8 v = *(const half8*)(hb + (size_t)s * NF + f8);
#pragma unroll
        for (int k = 0; k < 8; ++k) acc[k] += (float)v[k];
    }

    float dv = rsqrtf((float)cntr + 1.0f);
    float bb[8] = {b0.x, b0.y, b0.z, b0.w, b1.x, b1.y, b1.z, b1.w};
    half8 o8;
#pragma unroll
    for (int k = 0; k < 8; ++k) {
        float o = fmaxf(fmaf(dv, acc[k] + (float)sv[k], bb[k]), 0.f);
        o8[k] = (_Float16)o;
    }
    *(half8*)(out_h + obase) = o8;
}

// ---------- head: out[n,o] = h2[n,:] @ Wl[:,o] + bl[o]  (fp16 in, fp32 out) ----------

__global__ __launch_bounds__(256) void head_kernel(
    const _Float16* __restrict__ in, const float* __restrict__ Wl,
    const float* __restrict__ bl, float* __restrict__ out, int M) {
    __shared__ float Ws[NF * OUT_F];  // 32 KB
    int tid = threadIdx.x;
    for (int i = tid; i < NF * OUT_F; i += 256) Ws[i] = Wl[i];
    __syncthreads();
    int node = blockIdx.x * 16 + (tid >> 4);
    int o = tid & 15;
    if (node >= M) return;
    const half8* row8 = (const half8*)(in + (size_t)node * NF);
    float acc = 0.f;
#pragma unroll 2
    for (int k8 = 0; k8 < NF / 8; ++k8) {
        half8 hv = row8[k8];
        int kb = k8 * 8;
#pragma unroll
        for (int u = 0; u < 8; ++u)
            acc = fmaf((float)hv[u], Ws[(kb + u) * OUT_F + o], acc);
    }
    out[(size_t)node * OUT_F + o] = acc + bl[o];
}

// ---------- launch ----------

extern "C" void kernel_launch(void* const* d_in, const int* in_sizes, int n_in,
                              void* d_out, int out_size, void* d_ws, size_t ws_size,
                              hipStream_t stream) {
    const float* x  = (const float*)d_in[0];
    const int* eidx = (const int*)d_in[1];
    const float* W1 = (const float*)d_in[2];
    const float* b1 = (const float*)d_in[3];
    const float* W2 = (const float*)d_in[4];
    const float* b2 = (const float*)d_in[5];
    const float* Wl = (const float*)d_in[6];
    const float* bl = (const float*)d_in[7];

    int N = in_sizes[0] / NF;
    int E = in_sizes[1] / 2;
    int Mp = (N + GBM - 1) & ~(GBM - 1);
    const int* src = eidx;
    const int* dst = eidx + E;

    char* p = (char*)d_ws;
    auto carve = [&](size_t bytes) -> void* {
        void* r = (void*)p;
        p += (bytes + 255) & ~(size_t)255;
        return r;
    };
    _Float16* hbuf = (_Float16*)carve((size_t)Mp * NF * sizeof(_Float16));  // GEMM outputs
    _Float16* abuf = (_Float16*)carve((size_t)Mp * NF * sizeof(_Float16));  // x16 / agg outs
    _Float16* W1T  = (_Float16*)carve((size_t)NF * NF * sizeof(_Float16));
    _Float16* W2T  = (_Float16*)carve((size_t)NF * NF * sizeof(_Float16));
    int* counts    = (int*)carve((size_t)Mp * sizeof(int));
    int* src_pad   = (int*)carve((size_t)N * PAD_DEG * sizeof(int));

    hipMemsetAsync(counts, 0, (size_t)Mp * sizeof(int), stream);

    int xblocks = Mp / 4;
    int eblocks = (E + 255) / 256;
    prep_kernel<<<dim3(128 + xblocks + eblocks), dim3(256), 0, stream>>>(
        W1, W2, W1T, W2T, x, abuf, src, dst, counts, src_pad, E, N, Mp);

    int nstripes = Mp / GBM;                       // 157
    int spx = (nstripes + 7) / 8;                  // stripes per XCD (ceil)
    dim3 gg(8 * spx * 4);                          // 640 blocks, guarded in-kernel
    dim3 ga(Mp / 4);                               // one wave per node

    // layer 1
    gemm_mfma_kernel<<<gg, dim3(256), 0, stream>>>(abuf, W1T, counts, hbuf, nstripes);
    agg_kernel<<<ga, dim3(256), 0, stream>>>(hbuf, counts, src_pad, b1, abuf, N);
    // layer 2
    gemm_mfma_kernel<<<gg, dim3(256), 0, stream>>>(abuf, W2T, counts, hbuf, nstripes);
    agg_kernel<<<ga, dim3(256), 0, stream>>>(hbuf, counts, src_pad, b2, abuf, N);
    // head
    head_kernel<<<dim3((N + 15) / 16), dim3(256), 0, stream>>>(abuf, Wl, bl, (float*)d_out, N);
}